// Round 1
// baseline (683.998 us; speedup 1.0000x reference)
//
#include <hip/hip_runtime.h>

typedef unsigned short u16;
typedef __attribute__((ext_vector_type(8))) short short8;
typedef __attribute__((ext_vector_type(4))) float f32x4;

#define Bn 4096
#define Vn 20
#define Dn 768
#define Mn (Bn * Vn)   // 81920 rows
#define Nn (2 * Dn)    // 1536 interleaved m1/m2 columns

typedef __attribute__((address_space(1))) void GV;
typedef __attribute__((address_space(3))) void LV;

__device__ __forceinline__ u16 f2bf(float f) {
  union { float f; unsigned u; } v; v.f = f;
  unsigned r = v.u + 0x7FFFu + ((v.u >> 16) & 1u);  // round-to-nearest-even
  return (u16)(r >> 16);
}

// ---------------- kernel 1: row softmax -> bf16 X ----------------
__global__ __launch_bounds__(192) void softmax_k(const float* __restrict__ vf,
                                                 u16* __restrict__ X) {
  size_t row = blockIdx.x;
  const float4* p = (const float4*)(vf + row * Dn);
  int t = threadIdx.x;
  float4 v = p[t];
  float mx = fmaxf(fmaxf(v.x, v.y), fmaxf(v.z, v.w));
  #pragma unroll
  for (int off = 32; off; off >>= 1) mx = fmaxf(mx, __shfl_xor(mx, off));
  __shared__ float rr[3];
  __shared__ float rs[3];
  int wv = t >> 6, ln = t & 63;
  if (!ln) rr[wv] = mx;
  __syncthreads();
  mx = fmaxf(fmaxf(rr[0], rr[1]), rr[2]);
  float e0 = __expf(v.x - mx), e1 = __expf(v.y - mx);
  float e2 = __expf(v.z - mx), e3 = __expf(v.w - mx);
  float s = e0 + e1 + e2 + e3;
  #pragma unroll
  for (int off = 32; off; off >>= 1) s += __shfl_xor(s, off);
  if (!ln) rs[wv] = s;
  __syncthreads();
  float inv = 1.0f / (rs[0] + rs[1] + rs[2]);
  ushort4 o;
  o.x = f2bf(e0 * inv); o.y = f2bf(e1 * inv);
  o.z = f2bf(e2 * inv); o.w = f2bf(e3 * inv);
  ((ushort4*)(X + row * Dn))[t] = o;
}

// ------- kernel 2: pack W1/W2 interleaved, bf16, row-major [1536][768] -------
// Wt row (2j)   = W1 row j   (m1 column j)
// Wt row (2j+1) = W2 row j   (m2 column j)
__global__ __launch_bounds__(256) void build_wt_k(const float* __restrict__ W1,
                                                  const float* __restrict__ W2,
                                                  u16* __restrict__ Wt) {
  int idx = blockIdx.x * 256 + threadIdx.x;
  if (idx >= Dn * Dn) return;
  int j = idx / Dn, d = idx - j * Dn;
  Wt[(size_t)(2 * j) * Dn + d]     = f2bf(W1[(size_t)j * Dn + d]);
  Wt[(size_t)(2 * j + 1) * Dn + d] = f2bf(W2[(size_t)j * Dn + d]);
}

// ---------------- kernel 3: GEMM (M=81920, N=1536, K=768) + fuse epilogue ----
// C[row, 2e]   = m1[row, e],  C[row, 2e+1] = m2[row, e]
// epilogue: out[row, e] = relu(text[row/20, e] * m1 + m2)
__global__ __launch_bounds__(256) void gemm_fuse_k(
    const u16* __restrict__ X, const u16* __restrict__ Wt,
    const float* __restrict__ b1, const float* __restrict__ b2,
    const float* __restrict__ text, float* __restrict__ out) {
  __shared__ __align__(16) u16 As[128 * 64];
  __shared__ __align__(16) u16 Bs[128 * 64];
  const int t = threadIdx.x, w = t >> 6, l = t & 63;
  const int lo = l & 15, hi = l >> 4;
  const int brow = blockIdx.y * 128, bcol = blockIdx.x * 128;
  const int wr = w >> 1, wc = w & 1;
  f32x4 acc[4][4] = {};

  for (int k0 = 0; k0 < Dn; k0 += 64) {
    // stage A[128][64] and B[128][64] (both row-major along K), 16B chunks
    #pragma unroll
    for (int j = 0; j < 4; ++j) {
      const int qb = j * 256 + w * 64;   // wave-uniform chunk base
      const int q = qb + l;              // per-lane chunk: row = q>>3, col16 = q&7
      const u16* ga = X + (size_t)(brow + (q >> 3)) * Dn + k0 + (q & 7) * 8;
      __builtin_amdgcn_global_load_lds((GV*)ga, (LV*)(As + qb * 8), 16, 0, 0);
      const u16* gb = Wt + (size_t)(bcol + (q >> 3)) * Dn + k0 + (q & 7) * 8;
      __builtin_amdgcn_global_load_lds((GV*)gb, (LV*)(Bs + qb * 8), 16, 0, 0);
    }
    __syncthreads();
    #pragma unroll
    for (int kk = 0; kk < 2; ++kk) {
      short8 af[4], bfr[4];
      #pragma unroll
      for (int m = 0; m < 4; ++m)
        af[m] = *(const short8*)(As + (wr * 64 + m * 16 + lo) * 64 + kk * 32 + hi * 8);
      #pragma unroll
      for (int n = 0; n < 4; ++n)
        bfr[n] = *(const short8*)(Bs + (wc * 64 + n * 16 + lo) * 64 + kk * 32 + hi * 8);
      #pragma unroll
      for (int m = 0; m < 4; ++m)
        #pragma unroll
        for (int n = 0; n < 4; ++n)
          acc[m][n] = __builtin_amdgcn_mfma_f32_16x16x32_bf16(af[m], bfr[n], acc[m][n], 0, 0, 0);
    }
    __syncthreads();
  }

  // epilogue: lane parity == column parity (m1 on even lanes, m2 on odd)
  #pragma unroll
  for (int n = 0; n < 4; ++n) {
    const int gc = bcol + wc * 64 + n * 16 + lo;  // global col in [0,1536)
    const int e = gc >> 1;
    const float bias = (gc & 1) ? b2[e] : b1[e];
    #pragma unroll
    for (int m = 0; m < 4; ++m) {
      #pragma unroll
      for (int r = 0; r < 4; ++r) {
        const int gr = brow + wr * 64 + m * 16 + hi * 4 + r;  // global row
        float v = acc[m][n][r] + bias;
        float pp = __shfl_xor(v, 1);  // partner: other of {m1,m2} at same e
        if (!(l & 1)) {
          float tf = text[(size_t)(gr / Vn) * Dn + e];
          out[(size_t)gr * Dn + e] = fmaxf(tf * v + pp, 0.0f);
        }
      }
    }
  }
}

// ---------------- kernel 4: conv1 -> relu -> conv2, in-place per row --------
__global__ __launch_bounds__(192) void conv_k(float* __restrict__ out,
                                              const float* __restrict__ cw1,
                                              const float* __restrict__ cb1,
                                              const float* __restrict__ cw2,
                                              const float* __restrict__ cb2) {
  __shared__ float buf[Dn];
  __shared__ float tmp[Dn];
  size_t row = blockIdx.x;
  float* p = out + row * Dn;
  int t = threadIdx.x;
  float4 v = ((const float4*)p)[t];
  ((float4*)buf)[t] = v;
  const float w10 = cw1[0], w11 = cw1[1], w12 = cw1[2], c1b = cb1[0];
  const float w20 = cw2[0], w21 = cw2[1], w22 = cw2[2], c2b = cb2[0];
  __syncthreads();
  float lm = t ? buf[t * 4 - 1] : 0.0f;
  float rp = (t < 191) ? buf[t * 4 + 4] : 0.0f;
  float4 c;
  c.x = fmaxf(w10 * lm  + w11 * v.x + w12 * v.y + c1b, 0.0f);
  c.y = fmaxf(w10 * v.x + w11 * v.y + w12 * v.z + c1b, 0.0f);
  c.z = fmaxf(w10 * v.y + w11 * v.z + w12 * v.w + c1b, 0.0f);
  c.w = fmaxf(w10 * v.z + w11 * v.w + w12 * rp  + c1b, 0.0f);
  ((float4*)tmp)[t] = c;
  __syncthreads();
  float lm2 = t ? tmp[t * 4 - 1] : 0.0f;
  float rp2 = (t < 191) ? tmp[t * 4 + 4] : 0.0f;
  float4 o;
  o.x = w20 * lm2 + w21 * c.x + w22 * c.y + c2b;
  o.y = w20 * c.x + w21 * c.y + w22 * c.z + c2b;
  o.z = w20 * c.y + w21 * c.z + w22 * c.w + c2b;
  o.w = w20 * c.z + w21 * c.w + w22 * rp2 + c2b;
  ((float4*)p)[t] = o;
}

extern "C" void kernel_launch(void* const* d_in, const int* in_sizes, int n_in,
                              void* d_out, int out_size, void* d_ws, size_t ws_size,
                              hipStream_t stream) {
  const float* text = (const float*)d_in[0];
  const float* vf   = (const float*)d_in[1];
  const float* W1   = (const float*)d_in[2];
  const float* b1   = (const float*)d_in[3];
  const float* W2   = (const float*)d_in[4];
  const float* b2   = (const float*)d_in[5];
  const float* cw1  = (const float*)d_in[6];
  const float* cb1  = (const float*)d_in[7];
  const float* cw2  = (const float*)d_in[8];
  const float* cb2  = (const float*)d_in[9];
  float* out = (float*)d_out;

  u16* X  = (u16*)d_ws;                       // [81920][768] bf16 softmax
  u16* Wt = (u16*)d_ws + (size_t)Mn * Dn;     // [1536][768] bf16 packed weights

  softmax_k<<<Mn, 192, 0, stream>>>(vf, X);
  build_wt_k<<<(Dn * Dn + 255) / 256, 256, 0, stream>>>(W1, W2, Wt);
  dim3 grid(Nn / 128, Mn / 128);              // (12, 640); x-major => A-tile L2 reuse
  gemm_fuse_k<<<grid, 256, 0, stream>>>(X, Wt, b1, b2, text, out);
  conv_k<<<Mn, 192, 0, stream>>>(out, cw1, cb1, cw2, cb2);
}

// Round 2
// 500.563 us; speedup vs baseline: 1.3665x; 1.3665x over previous
//
#include <hip/hip_runtime.h>

typedef unsigned short u16;
typedef __attribute__((ext_vector_type(8))) short short8;
typedef __attribute__((ext_vector_type(4))) float f32x4;

#define Bn 4096
#define Vn 20
#define Dn 768
#define Mn (Bn * Vn)   // 81920 rows
#define Nn (2 * Dn)    // 1536 packed m1/m2 columns

typedef __attribute__((address_space(1))) void GV;
typedef __attribute__((address_space(3))) void LV;

__device__ __forceinline__ u16 f2bf(float f) {
  union { float f; unsigned u; } v; v.f = f;
  unsigned r = v.u + 0x7FFFu + ((v.u >> 16) & 1u);  // round-to-nearest-even
  return (u16)(r >> 16);
}

// ---------------- kernel 1: row softmax -> bf16 X ----------------
__global__ __launch_bounds__(192) void softmax_k(const float* __restrict__ vf,
                                                 u16* __restrict__ X) {
  size_t row = blockIdx.x;
  const float4* p = (const float4*)(vf + row * Dn);
  int t = threadIdx.x;
  float4 v = p[t];
  float mx = fmaxf(fmaxf(v.x, v.y), fmaxf(v.z, v.w));
  #pragma unroll
  for (int off = 32; off; off >>= 1) mx = fmaxf(mx, __shfl_xor(mx, off));
  __shared__ float rr[3];
  __shared__ float rs[3];
  int wv = t >> 6, ln = t & 63;
  if (!ln) rr[wv] = mx;
  __syncthreads();
  mx = fmaxf(fmaxf(rr[0], rr[1]), rr[2]);
  float e0 = __expf(v.x - mx), e1 = __expf(v.y - mx);
  float e2 = __expf(v.z - mx), e3 = __expf(v.w - mx);
  float s = e0 + e1 + e2 + e3;
  #pragma unroll
  for (int off = 32; off; off >>= 1) s += __shfl_xor(s, off);
  if (!ln) rs[wv] = s;
  __syncthreads();
  float inv = 1.0f / (rs[0] + rs[1] + rs[2]);
  ushort4 o;
  o.x = f2bf(e0 * inv); o.y = f2bf(e1 * inv);
  o.z = f2bf(e2 * inv); o.w = f2bf(e3 * inv);
  ((ushort4*)(X + row * Dn))[t] = o;
}

// ------- kernel 2: pack W1/W2 block-of-32 interleaved, bf16 [1536][768] -----
// For source col j (0..767): b = j>>5, c = j&31
//   Wt row (b*64 +      c) = W1 row j
//   Wt row (b*64 + 32 + c) = W2 row j
// => a 64-row span [g*64, g*64+64) holds W1 cols [g*32,g*32+32) then W2 same.
__global__ __launch_bounds__(256) void build_wt_k(const float* __restrict__ W1,
                                                  const float* __restrict__ W2,
                                                  u16* __restrict__ Wt) {
  int idx = blockIdx.x * 256 + threadIdx.x;
  if (idx >= Dn * Dn) return;
  int j = idx / Dn, d = idx - j * Dn;
  int b = j >> 5, c = j & 31;
  Wt[(size_t)(b * 64 + c) * Dn + d]      = f2bf(W1[(size_t)j * Dn + d]);
  Wt[(size_t)(b * 64 + 32 + c) * Dn + d] = f2bf(W2[(size_t)j * Dn + d]);
}

// ---------------- kernel 3: GEMM (M=81920, N=1536, K=768) + fuse epilogue ----
// Wave wc covers Wt rows [bx*128 + wc*64, +64): n=0,1 -> m1 cols, n=2,3 -> m2
// at the SAME e = bx*64 + wc*32 + (n&1)*16 + lo.  Fusion needs no shfl; all
// 64 lanes store, 16 consecutive e per 16-lane group => full 64B lines.
__global__ __launch_bounds__(256) void gemm_fuse_k(
    const u16* __restrict__ X, const u16* __restrict__ Wt,
    const float* __restrict__ b1, const float* __restrict__ b2,
    const float* __restrict__ text, float* __restrict__ out) {
  __shared__ __align__(16) u16 As[128 * 64];
  __shared__ __align__(16) u16 Bs[128 * 64];
  // T1: bijective XCD swizzle (7680 % 8 == 0). Consecutive logical blocks
  // (which share an A-panel across the 12 N-tiles) land on the SAME XCD.
  const int h = blockIdx.x;
  const int lin = (h & 7) * (7680 / 8) + (h >> 3);
  const int by = lin / 12, bx = lin - by * 12;

  const int t = threadIdx.x, w = t >> 6, l = t & 63;
  const int lo = l & 15, hi = l >> 4;
  const int brow = by * 128;
  const int wr = w >> 1, wc = w & 1;
  f32x4 acc[4][4] = {};

  for (int k0 = 0; k0 < Dn; k0 += 64) {
    // stage A[128][64] and B[128][64] (row-major along K), 16B chunks
    #pragma unroll
    for (int j = 0; j < 4; ++j) {
      const int qb = j * 256 + w * 64;   // wave-uniform chunk base
      const int q = qb + l;              // per-lane chunk: row = q>>3, col16 = q&7
      const u16* ga = X + (size_t)(brow + (q >> 3)) * Dn + k0 + (q & 7) * 8;
      __builtin_amdgcn_global_load_lds((GV*)ga, (LV*)(As + qb * 8), 16, 0, 0);
      const u16* gb = Wt + (size_t)(bx * 128 + (q >> 3)) * Dn + k0 + (q & 7) * 8;
      __builtin_amdgcn_global_load_lds((GV*)gb, (LV*)(Bs + qb * 8), 16, 0, 0);
    }
    __syncthreads();
    #pragma unroll
    for (int kk = 0; kk < 2; ++kk) {
      short8 af[4], bfr[4];
      #pragma unroll
      for (int m = 0; m < 4; ++m)
        af[m] = *(const short8*)(As + (wr * 64 + m * 16 + lo) * 64 + kk * 32 + hi * 8);
      #pragma unroll
      for (int n = 0; n < 4; ++n)
        bfr[n] = *(const short8*)(Bs + (wc * 64 + n * 16 + lo) * 64 + kk * 32 + hi * 8);
      #pragma unroll
      for (int m = 0; m < 4; ++m)
        #pragma unroll
        for (int n = 0; n < 4; ++n)
          acc[m][n] = __builtin_amdgcn_mfma_f32_16x16x32_bf16(af[m], bfr[n], acc[m][n], 0, 0, 0);
    }
    __syncthreads();
  }

  // epilogue: m1 in acc[m][n], m2 in acc[m][n+2], same lane, same e.
  const int ebase = bx * 64 + wc * 32;
  #pragma unroll
  for (int n = 0; n < 2; ++n) {
    const int e = ebase + n * 16 + lo;
    const float B1 = b1[e], B2 = b2[e];
    #pragma unroll
    for (int m = 0; m < 4; ++m) {
      #pragma unroll
      for (int r = 0; r < 4; ++r) {
        const int gr = brow + wr * 64 + m * 16 + hi * 4 + r;  // global row
        const float v1 = acc[m][n][r] + B1;
        const float v2 = acc[m][n + 2][r] + B2;
        const float tf = text[(size_t)(gr / Vn) * Dn + e];
        out[(size_t)gr * Dn + e] = fmaxf(tf * v1 + v2, 0.0f);
      }
    }
  }
}

// ---------------- kernel 4: conv1 -> relu -> conv2, in-place per row --------
__global__ __launch_bounds__(192) void conv_k(float* __restrict__ out,
                                              const float* __restrict__ cw1,
                                              const float* __restrict__ cb1,
                                              const float* __restrict__ cw2,
                                              const float* __restrict__ cb2) {
  __shared__ float buf[Dn];
  __shared__ float tmp[Dn];
  size_t row = blockIdx.x;
  float* p = out + row * Dn;
  int t = threadIdx.x;
  float4 v = ((const float4*)p)[t];
  ((float4*)buf)[t] = v;
  const float w10 = cw1[0], w11 = cw1[1], w12 = cw1[2], c1b = cb1[0];
  const float w20 = cw2[0], w21 = cw2[1], w22 = cw2[2], c2b = cb2[0];
  __syncthreads();
  float lm = t ? buf[t * 4 - 1] : 0.0f;
  float rp = (t < 191) ? buf[t * 4 + 4] : 0.0f;
  float4 c;
  c.x = fmaxf(w10 * lm  + w11 * v.x + w12 * v.y + c1b, 0.0f);
  c.y = fmaxf(w10 * v.x + w11 * v.y + w12 * v.z + c1b, 0.0f);
  c.z = fmaxf(w10 * v.y + w11 * v.z + w12 * v.w + c1b, 0.0f);
  c.w = fmaxf(w10 * v.z + w11 * v.w + w12 * rp  + c1b, 0.0f);
  ((float4*)tmp)[t] = c;
  __syncthreads();
  float lm2 = t ? tmp[t * 4 - 1] : 0.0f;
  float rp2 = (t < 191) ? tmp[t * 4 + 4] : 0.0f;
  float4 o;
  o.x = w20 * lm2 + w21 * c.x + w22 * c.y + c2b;
  o.y = w20 * c.x + w21 * c.y + w22 * c.z + c2b;
  o.z = w20 * c.y + w21 * c.z + w22 * c.w + c2b;
  o.w = w20 * c.z + w21 * c.w + w22 * rp2 + c2b;
  ((float4*)p)[t] = o;
}

extern "C" void kernel_launch(void* const* d_in, const int* in_sizes, int n_in,
                              void* d_out, int out_size, void* d_ws, size_t ws_size,
                              hipStream_t stream) {
  const float* text = (const float*)d_in[0];
  const float* vf   = (const float*)d_in[1];
  const float* W1   = (const float*)d_in[2];
  const float* b1   = (const float*)d_in[3];
  const float* W2   = (const float*)d_in[4];
  const float* b2   = (const float*)d_in[5];
  const float* cw1  = (const float*)d_in[6];
  const float* cb1  = (const float*)d_in[7];
  const float* cw2  = (const float*)d_in[8];
  const float* cb2  = (const float*)d_in[9];
  float* out = (float*)d_out;

  u16* X  = (u16*)d_ws;                       // [81920][768] bf16 softmax
  u16* Wt = (u16*)d_ws + (size_t)Mn * Dn;     // [1536][768] bf16 packed weights

  softmax_k<<<Mn, 192, 0, stream>>>(vf, X);
  build_wt_k<<<(Dn * Dn + 255) / 256, 256, 0, stream>>>(W1, W2, Wt);
  gemm_fuse_k<<<(Nn / 128) * (Mn / 128), 256, 0, stream>>>(X, Wt, b1, b2, text, out);
  conv_k<<<Mn, 192, 0, stream>>>(out, cw1, cb1, cw2, cb2);
}

// Round 4
// 406.295 us; speedup vs baseline: 1.6835x; 1.2320x over previous
//
#include <hip/hip_runtime.h>

typedef unsigned short u16;
typedef __attribute__((ext_vector_type(8))) short short8;
typedef __attribute__((ext_vector_type(4))) float f32x4;

#define Bn 4096
#define Vn 20
#define Dn 768
#define Mn (Bn * Vn)   // 81920 rows
#define Nn (2 * Dn)    // 1536 packed m1/m2 columns

#define BM 256
#define BNt 128            // Wt rows per block tile (= 64 output e-columns)
#define BK 64
#define KT (Dn / BK)       // 12 K-tiles
#define NTILES (Nn / BNt)  // 12 N-tiles
#define GRID ((Mn / BM) * NTILES)   // 320 * 12 = 3840, %8 == 0
#define BUFE 24576         // u16 per LDS buffer: A 256x64 + B 128x64

typedef __attribute__((address_space(1))) void GV;
typedef __attribute__((address_space(3))) void LV;

__device__ __forceinline__ u16 f2bf(float f) {
  union { float f; unsigned u; } v; v.f = f;
  unsigned r = v.u + 0x7FFFu + ((v.u >> 16) & 1u);  // round-to-nearest-even
  return (u16)(r >> 16);
}

// ---------------- kernel 1: row softmax -> bf16 X ----------------
__global__ __launch_bounds__(192) void softmax_k(const float* __restrict__ vf,
                                                 u16* __restrict__ X) {
  size_t row = blockIdx.x;
  const float4* p = (const float4*)(vf + row * Dn);
  int t = threadIdx.x;
  float4 v = p[t];
  float mx = fmaxf(fmaxf(v.x, v.y), fmaxf(v.z, v.w));
  #pragma unroll
  for (int off = 32; off; off >>= 1) mx = fmaxf(mx, __shfl_xor(mx, off));
  __shared__ float rr[3];
  __shared__ float rs[3];
  int wv = t >> 6, ln = t & 63;
  if (!ln) rr[wv] = mx;
  __syncthreads();
  mx = fmaxf(fmaxf(rr[0], rr[1]), rr[2]);
  float e0 = __expf(v.x - mx), e1 = __expf(v.y - mx);
  float e2 = __expf(v.z - mx), e3 = __expf(v.w - mx);
  float s = e0 + e1 + e2 + e3;
  #pragma unroll
  for (int off = 32; off; off >>= 1) s += __shfl_xor(s, off);
  if (!ln) rs[wv] = s;
  __syncthreads();
  float inv = 1.0f / (rs[0] + rs[1] + rs[2]);
  ushort4 o;
  o.x = f2bf(e0 * inv); o.y = f2bf(e1 * inv);
  o.z = f2bf(e2 * inv); o.w = f2bf(e3 * inv);
  ((ushort4*)(X + row * Dn))[t] = o;
}

// ------- kernel 2: pack W1/W2 block-of-32 interleaved, bf16 [1536][768] -----
__global__ __launch_bounds__(256) void build_wt_k(const float* __restrict__ W1,
                                                  const float* __restrict__ W2,
                                                  u16* __restrict__ Wt) {
  int idx = blockIdx.x * 256 + threadIdx.x;
  if (idx >= Dn * Dn) return;
  int j = idx / Dn, d = idx - j * Dn;
  int b = j >> 5, c = j & 31;
  Wt[(size_t)(b * 64 + c) * Dn + d]      = f2bf(W1[(size_t)j * Dn + d]);
  Wt[(size_t)(b * 64 + 32 + c) * Dn + d] = f2bf(W2[(size_t)j * Dn + d]);
}

// ---------------- kernel 3: GEMM + fuse, 3-stage counted-vmcnt pipeline -----
// 8 waves: wr = w>>1 (4 in M, 64 rows each), wc = w&1 (2 in N, 64 Wt-rows).
// LDS: 3 buffers x (A[256][64] + B[128][64]) bf16, chunk-XOR swizzled.
// Per K-tile: vmcnt(6) (1 tile in flight) -> barrier -> 2 phases of
// {3x gload_lds prefetch || 8x ds_read_b128 -> lgkm0 -> 16 MFMA} -> barrier.
__global__ __launch_bounds__(512, 2) void gemm_fuse_k(
    const u16* __restrict__ X, const u16* __restrict__ Wt,
    const float* __restrict__ b1, const float* __restrict__ b2,
    const float* __restrict__ text, float* __restrict__ out) {
  __shared__ __align__(16) u16 smem[3 * BUFE];   // 144 KiB

  const int h = blockIdx.x;                      // GRID = 3840 blocks, %8==0
  const int lin = (h & 7) * (GRID / 8) + (h >> 3);
  const int by = lin / NTILES, bx = lin - by * NTILES;
  const int brow = by * BM;

  const int t = threadIdx.x, w = t >> 6, l = t & 63;
  const int lo = l & 15, hi = l >> 4;
  const int wr = w >> 1, wc = w & 1;

  // per-lane pre-swizzled global sources (rule #21: swizzle source + read)
  const u16* pA[4];
  const u16* pB[2];
  #pragma unroll
  for (int i = 0; i < 4; ++i) {
    int q = i * 512 + w * 64 + l;
    int row = q >> 3, c = q & 7;
    pA[i] = X + (size_t)(brow + row) * Dn + (c ^ (row & 7)) * 8;
  }
  #pragma unroll
  for (int i = 0; i < 2; ++i) {
    int q = i * 512 + w * 64 + l;
    int row = q >> 3, c = q & 7;
    pB[i] = Wt + (size_t)(bx * BNt + row) * Dn + (c ^ (row & 7)) * 8;
  }
  int koff = 0;  // K offset (elements) of next tile to stage

#define STAGE_A(i, sb) __builtin_amdgcn_global_load_lds( \
    (GV*)(pA[i] + koff), (LV*)(smem + (sb) * BUFE + ((i) * 512 + w * 64) * 8), 16, 0, 0)
#define STAGE_B(i, sb) __builtin_amdgcn_global_load_lds( \
    (GV*)(pB[i] + koff), (LV*)(smem + (sb) * BUFE + 16384 + ((i) * 512 + w * 64) * 8), 16, 0, 0)

  // prologue: tile 0 -> buf0, tile 1 -> buf1 (12 loads in flight)
  STAGE_A(0, 0); STAGE_A(1, 0); STAGE_A(2, 0); STAGE_A(3, 0);
  STAGE_B(0, 0); STAGE_B(1, 0);
  koff += BK;
  STAGE_A(0, 1); STAGE_A(1, 1); STAGE_A(2, 1); STAGE_A(3, 1);
  STAGE_B(0, 1); STAGE_B(1, 1);
  koff += BK;

  f32x4 acc[4][4] = {};
  int buf = 0, sbuf = 2;

  for (int kt = 0; kt < KT; ++kt) {
    // T4: counted wait — tile kt resident, tile kt+1 (6 loads) stays in flight
    if (kt < KT - 1) asm volatile("s_waitcnt vmcnt(6)" ::: "memory");
    else             asm volatile("s_waitcnt vmcnt(0)" ::: "memory");
    __builtin_amdgcn_s_barrier();
    const bool st = (kt < KT - 2);
    const u16* sa = smem + buf * BUFE;
    const u16* sb = sa + 16384;

    // ---- phase kk=0 ----
    if (st) { STAGE_A(0, sbuf); STAGE_A(1, sbuf); STAGE_B(0, sbuf); }
    short8 af[4], bfr[4];
    #pragma unroll
    for (int m = 0; m < 4; ++m) {
      int row = wr * 64 + m * 16 + lo;
      af[m] = *(const short8*)(sa + row * 64 + (hi ^ (row & 7)) * 8);
    }
    #pragma unroll
    for (int n = 0; n < 4; ++n) {
      int row = wc * 64 + n * 16 + lo;
      bfr[n] = *(const short8*)(sb + row * 64 + (hi ^ (row & 7)) * 8);
    }
    asm volatile("s_waitcnt lgkmcnt(0)" ::: "memory");
    __builtin_amdgcn_sched_barrier(0);
    __builtin_amdgcn_s_setprio(1);
    #pragma unroll
    for (int m = 0; m < 4; ++m)
      #pragma unroll
      for (int n = 0; n < 4; ++n)
        acc[m][n] = __builtin_amdgcn_mfma_f32_16x16x32_bf16(af[m], bfr[n], acc[m][n], 0, 0, 0);
    __builtin_amdgcn_s_setprio(0);
    __builtin_amdgcn_s_barrier();

    // ---- phase kk=1 ----
    if (st) { STAGE_A(2, sbuf); STAGE_A(3, sbuf); STAGE_B(1, sbuf); }
    #pragma unroll
    for (int m = 0; m < 4; ++m) {
      int row = wr * 64 + m * 16 + lo;
      af[m] = *(const short8*)(sa + row * 64 + ((4 + hi) ^ (row & 7)) * 8);
    }
    #pragma unroll
    for (int n = 0; n < 4; ++n) {
      int row = wc * 64 + n * 16 + lo;
      bfr[n] = *(const short8*)(sb + row * 64 + ((4 + hi) ^ (row & 7)) * 8);
    }
    asm volatile("s_waitcnt lgkmcnt(0)" ::: "memory");
    __builtin_amdgcn_sched_barrier(0);
    __builtin_amdgcn_s_setprio(1);
    #pragma unroll
    for (int m = 0; m < 4; ++m)
      #pragma unroll
      for (int n = 0; n < 4; ++n)
        acc[m][n] = __builtin_amdgcn_mfma_f32_16x16x32_bf16(af[m], bfr[n], acc[m][n], 0, 0, 0);
    __builtin_amdgcn_s_setprio(0);
    __builtin_amdgcn_s_barrier();

    if (st) koff += BK;
    buf  = (buf  == 2) ? 0 : buf + 1;
    sbuf = (sbuf == 2) ? 0 : sbuf + 1;
  }
#undef STAGE_A
#undef STAGE_B

  // epilogue: m1 = acc[m][n], m2 = acc[m][n+2], same lane, same e
  const int ebase = (bx * 2 + wc) * 32;
  #pragma unroll
  for (int n = 0; n < 2; ++n) {
    const int e = ebase + n * 16 + lo;
    const float B1 = b1[e], B2 = b2[e];
    #pragma unroll
    for (int m = 0; m < 4; ++m) {
      const int gr0 = brow + wr * 64 + m * 16 + hi * 4;
      #pragma unroll
      for (int r = 0; r < 4; ++r) {
        const int gr = gr0 + r;
        const float v1 = acc[m][n][r] + B1;
        const float v2 = acc[m][n + 2][r] + B2;
        const float tf = text[(size_t)(gr / Vn) * Dn + e];
        out[(size_t)gr * Dn + e] = fmaxf(tf * v1 + v2, 0.0f);
      }
    }
  }
}

// ---------------- kernel 4: conv1 -> relu -> conv2, in-place per row --------
__global__ __launch_bounds__(192) void conv_k(float* __restrict__ out,
                                              const float* __restrict__ cw1,
                                              const float* __restrict__ cb1,
                                              const float* __restrict__ cw2,
                                              const float* __restrict__ cb2) {
  __shared__ float buf[Dn];
  __shared__ float tmp[Dn];
  size_t row = blockIdx.x;
  float* p = out + row * Dn;
  int t = threadIdx.x;
  float4 v = ((const float4*)p)[t];
  ((float4*)buf)[t] = v;
  const float w10 = cw1[0], w11 = cw1[1], w12 = cw1[2], c1b = cb1[0];
  const float w20 = cw2[0], w21 = cw2[1], w22 = cw2[2], c2b = cb2[0];
  __syncthreads();
  float lm = t ? buf[t * 4 - 1] : 0.0f;
  float rp = (t < 191) ? buf[t * 4 + 4] : 0.0f;
  float4 c;
  c.x = fmaxf(w10 * lm  + w11 * v.x + w12 * v.y + c1b, 0.0f);
  c.y = fmaxf(w10 * v.x + w11 * v.y + w12 * v.z + c1b, 0.0f);
  c.z = fmaxf(w10 * v.y + w11 * v.z + w12 * v.w + c1b, 0.0f);
  c.w = fmaxf(w10 * v.z + w11 * v.w + w12 * rp  + c1b, 0.0f);
  ((float4*)tmp)[t] = c;
  __syncthreads();
  float lm2 = t ? tmp[t * 4 - 1] : 0.0f;
  float rp2 = (t < 191) ? tmp[t * 4 + 4] : 0.0f;
  float4 o;
  o.x = w20 * lm2 + w21 * c.x + w22 * c.y + c2b;
  o.y = w20 * c.x + w21 * c.y + w22 * c.z + c2b;
  o.z = w20 * c.y + w21 * c.z + w22 * c.w + c2b;
  o.w = w20 * c.z + w21 * c.w + w22 * rp2 + c2b;
  ((float4*)p)[t] = o;
}

extern "C" void kernel_launch(void* const* d_in, const int* in_sizes, int n_in,
                              void* d_out, int out_size, void* d_ws, size_t ws_size,
                              hipStream_t stream) {
  const float* text = (const float*)d_in[0];
  const float* vf   = (const float*)d_in[1];
  const float* W1   = (const float*)d_in[2];
  const float* b1   = (const float*)d_in[3];
  const float* W2   = (const float*)d_in[4];
  const float* b2   = (const float*)d_in[5];
  const float* cw1  = (const float*)d_in[6];
  const float* cb1  = (const float*)d_in[7];
  const float* cw2  = (const float*)d_in[8];
  const float* cb2  = (const float*)d_in[9];
  float* out = (float*)d_out;

  u16* X  = (u16*)d_ws;                       // [81920][768] bf16 softmax
  u16* Wt = (u16*)d_ws + (size_t)Mn * Dn;     // [1536][768] bf16 packed weights

  softmax_k<<<Mn, 192, 0, stream>>>(vf, X);
  build_wt_k<<<(Dn * Dn + 255) / 256, 256, 0, stream>>>(W1, W2, Wt);
  gemm_fuse_k<<<GRID, 512, 0, stream>>>(X, Wt, b1, b2, text, out);
  conv_k<<<Mn, 192, 0, stream>>>(out, cw1, cb1, cw2, cb2);
}

// Round 5
// 402.266 us; speedup vs baseline: 1.7004x; 1.0100x over previous
//
#include <hip/hip_runtime.h>

typedef unsigned short u16;
typedef __attribute__((ext_vector_type(8))) short short8;
typedef __attribute__((ext_vector_type(4))) float f32x4;

#define Bn 4096
#define Vn 20
#define Dn 768
#define Mn (Bn * Vn)   // 81920 rows
#define Nn (2 * Dn)    // 1536 packed m1/m2 columns

#define BM 256
#define BNt 256            // Wt rows per block tile (= 128 output e-columns)
#define BK 64
#define KT (Dn / BK)       // 12 K-tiles
#define NTILES (Nn / BNt)  // 6 N-tiles
#define GRID ((Mn / BM) * NTILES)   // 320 * 6 = 1920, %8 == 0
#define BUFE 32768         // u16 per LDS buffer: A 256x64 + B 256x64

typedef __attribute__((address_space(1))) void GV;
typedef __attribute__((address_space(3))) void LV;

__device__ __forceinline__ u16 f2bf(float f) {
  union { float f; unsigned u; } v; v.f = f;
  unsigned r = v.u + 0x7FFFu + ((v.u >> 16) & 1u);  // round-to-nearest-even
  return (u16)(r >> 16);
}

// ---------------- kernel 1: row softmax -> bf16 X ----------------
__global__ __launch_bounds__(192) void softmax_k(const float* __restrict__ vf,
                                                 u16* __restrict__ X) {
  size_t row = blockIdx.x;
  const float4* p = (const float4*)(vf + row * Dn);
  int t = threadIdx.x;
  float4 v = p[t];
  float mx = fmaxf(fmaxf(v.x, v.y), fmaxf(v.z, v.w));
  #pragma unroll
  for (int off = 32; off; off >>= 1) mx = fmaxf(mx, __shfl_xor(mx, off));
  __shared__ float rr[3];
  __shared__ float rs[3];
  int wv = t >> 6, ln = t & 63;
  if (!ln) rr[wv] = mx;
  __syncthreads();
  mx = fmaxf(fmaxf(rr[0], rr[1]), rr[2]);
  float e0 = __expf(v.x - mx), e1 = __expf(v.y - mx);
  float e2 = __expf(v.z - mx), e3 = __expf(v.w - mx);
  float s = e0 + e1 + e2 + e3;
  #pragma unroll
  for (int off = 32; off; off >>= 1) s += __shfl_xor(s, off);
  if (!ln) rs[wv] = s;
  __syncthreads();
  float inv = 1.0f / (rs[0] + rs[1] + rs[2]);
  ushort4 o;
  o.x = f2bf(e0 * inv); o.y = f2bf(e1 * inv);
  o.z = f2bf(e2 * inv); o.w = f2bf(e3 * inv);
  ((ushort4*)(X + row * Dn))[t] = o;
}

// ------- kernel 2: pack W1/W2 block-of-32 interleaved, bf16 [1536][768] -----
__global__ __launch_bounds__(256) void build_wt_k(const float* __restrict__ W1,
                                                  const float* __restrict__ W2,
                                                  u16* __restrict__ Wt) {
  int idx = blockIdx.x * 256 + threadIdx.x;
  if (idx >= Dn * Dn) return;
  int j = idx / Dn, d = idx - j * Dn;
  int b = j >> 5, c = j & 31;
  Wt[(size_t)(b * 64 + c) * Dn + d]      = f2bf(W1[(size_t)j * Dn + d]);
  Wt[(size_t)(b * 64 + 32 + c) * Dn + d] = f2bf(W2[(size_t)j * Dn + d]);
}

// -------- kernel 3: GEMM + fuse, 256x256 tile, 128x64 wave tile -------------
// 8 waves: wrr = w>>2 (2 in M, 128 rows each), wcc = w&3 (4 in N, 64 Wt-rows).
// LDS: 2 buffers x (A[256][64] + B[256][64]) bf16, chunk-XOR swizzled.
// Per K-tile: vmcnt(0) -> barrier -> stage kt+1 (other buffer) -> 4 phases of
// {ds_read -> lgkm0 -> setprio 16 MFMA}, NO inner barriers (read buffer is
// never written this iteration; overwrite hazard guarded by the top barrier).
__global__ __launch_bounds__(512, 2) void gemm_fuse_k(
    const u16* __restrict__ X, const u16* __restrict__ Wt,
    const float* __restrict__ b1, const float* __restrict__ b2,
    const float* __restrict__ text, float* __restrict__ out) {
  __shared__ __align__(16) u16 smem[2 * BUFE];   // 128 KiB

  const int h = blockIdx.x;                      // GRID = 1920 blocks, %8==0
  const int lin = (h & 7) * (GRID / 8) + (h >> 3);
  const int by = lin / NTILES, bx = lin - by * NTILES;
  const int brow = by * BM;

  const int t = threadIdx.x, w = t >> 6, l = t & 63;
  const int lo = l & 15, hi = l >> 4;
  const int wrr = w >> 2, wcc = w & 3;

  // per-lane pre-swizzled global sources (swizzle source + read, LDS linear)
  const u16* pA[4];
  const u16* pB[4];
  #pragma unroll
  for (int i = 0; i < 4; ++i) {
    int q = i * 512 + t;
    int row = q >> 3, c = q & 7;
    pA[i] = X + (size_t)(brow + row) * Dn + (c ^ (row & 7)) * 8;
    pB[i] = Wt + (size_t)(bx * BNt + row) * Dn + (c ^ (row & 7)) * 8;
  }

#define STAGE_ALL(sb, koff) do {                                              \
    _Pragma("unroll")                                                         \
    for (int i = 0; i < 4; ++i) {                                             \
      __builtin_amdgcn_global_load_lds((GV*)(pA[i] + (koff)),                 \
          (LV*)(smem + (sb) * BUFE + (i * 512 + w * 64) * 8), 16, 0, 0);      \
      __builtin_amdgcn_global_load_lds((GV*)(pB[i] + (koff)),                 \
          (LV*)(smem + (sb) * BUFE + 16384 + (i * 512 + w * 64) * 8), 16, 0, 0); \
    }                                                                         \
  } while (0)

  STAGE_ALL(0, 0);  // prologue: tile 0 -> buf0

  f32x4 acc[8][4] = {};

  for (int kt = 0; kt < KT; ++kt) {
    asm volatile("s_waitcnt vmcnt(0)" ::: "memory");
    __builtin_amdgcn_s_barrier();
    if (kt < KT - 1) STAGE_ALL((kt + 1) & 1, (kt + 1) * BK);

    const u16* sa = smem + (kt & 1) * BUFE;
    const u16* sb = sa + 16384;
    short8 af[4], bfr[4];

    // ---- phase 0: kk=0, m-rows 0..63 ----
    #pragma unroll
    for (int m = 0; m < 4; ++m) {
      int row = wrr * 128 + m * 16 + lo;
      af[m] = *(const short8*)(sa + row * 64 + (hi ^ (row & 7)) * 8);
    }
    #pragma unroll
    for (int n = 0; n < 4; ++n) {
      int row = wcc * 64 + n * 16 + lo;
      bfr[n] = *(const short8*)(sb + row * 64 + (hi ^ (row & 7)) * 8);
    }
    asm volatile("s_waitcnt lgkmcnt(0)" ::: "memory");
    __builtin_amdgcn_sched_barrier(0);
    __builtin_amdgcn_s_setprio(1);
    #pragma unroll
    for (int m = 0; m < 4; ++m)
      #pragma unroll
      for (int n = 0; n < 4; ++n)
        acc[m][n] = __builtin_amdgcn_mfma_f32_16x16x32_bf16(af[m], bfr[n], acc[m][n], 0, 0, 0);
    __builtin_amdgcn_s_setprio(0);

    // ---- phase 1: kk=0, m-rows 64..127 (bfr reused) ----
    #pragma unroll
    for (int m = 0; m < 4; ++m) {
      int row = wrr * 128 + 64 + m * 16 + lo;
      af[m] = *(const short8*)(sa + row * 64 + (hi ^ (row & 7)) * 8);
    }
    asm volatile("s_waitcnt lgkmcnt(0)" ::: "memory");
    __builtin_amdgcn_sched_barrier(0);
    __builtin_amdgcn_s_setprio(1);
    #pragma unroll
    for (int m = 0; m < 4; ++m)
      #pragma unroll
      for (int n = 0; n < 4; ++n)
        acc[m + 4][n] = __builtin_amdgcn_mfma_f32_16x16x32_bf16(af[m], bfr[n], acc[m + 4][n], 0, 0, 0);
    __builtin_amdgcn_s_setprio(0);

    // ---- phase 2: kk=1, m-rows 0..63 ----
    #pragma unroll
    for (int m = 0; m < 4; ++m) {
      int row = wrr * 128 + m * 16 + lo;
      af[m] = *(const short8*)(sa + row * 64 + ((4 + hi) ^ (row & 7)) * 8);
    }
    #pragma unroll
    for (int n = 0; n < 4; ++n) {
      int row = wcc * 64 + n * 16 + lo;
      bfr[n] = *(const short8*)(sb + row * 64 + ((4 + hi) ^ (row & 7)) * 8);
    }
    asm volatile("s_waitcnt lgkmcnt(0)" ::: "memory");
    __builtin_amdgcn_sched_barrier(0);
    __builtin_amdgcn_s_setprio(1);
    #pragma unroll
    for (int m = 0; m < 4; ++m)
      #pragma unroll
      for (int n = 0; n < 4; ++n)
        acc[m][n] = __builtin_amdgcn_mfma_f32_16x16x32_bf16(af[m], bfr[n], acc[m][n], 0, 0, 0);
    __builtin_amdgcn_s_setprio(0);

    // ---- phase 3: kk=1, m-rows 64..127 ----
    #pragma unroll
    for (int m = 0; m < 4; ++m) {
      int row = wrr * 128 + 64 + m * 16 + lo;
      af[m] = *(const short8*)(sa + row * 64 + ((4 + hi) ^ (row & 7)) * 8);
    }
    asm volatile("s_waitcnt lgkmcnt(0)" ::: "memory");
    __builtin_amdgcn_sched_barrier(0);
    __builtin_amdgcn_s_setprio(1);
    #pragma unroll
    for (int m = 0; m < 4; ++m)
      #pragma unroll
      for (int n = 0; n < 4; ++n)
        acc[m + 4][n] = __builtin_amdgcn_mfma_f32_16x16x32_bf16(af[m], bfr[n], acc[m + 4][n], 0, 0, 0);
    __builtin_amdgcn_s_setprio(0);
  }
#undef STAGE_ALL

  // epilogue: group g = bx*4 + wcc; m1 = acc[m][n], m2 = acc[m][n+2], same e
  const int ebase = (bx * 4 + wcc) * 32;
  #pragma unroll
  for (int n = 0; n < 2; ++n) {
    const int e = ebase + n * 16 + lo;
    const float B1 = b1[e], B2 = b2[e];
    #pragma unroll
    for (int m = 0; m < 8; ++m) {
      const int gr0 = brow + wrr * 128 + m * 16 + hi * 4;
      #pragma unroll
      for (int r = 0; r < 4; ++r) {
        const int gr = gr0 + r;
        const float v1 = acc[m][n][r] + B1;
        const float v2 = acc[m][n + 2][r] + B2;
        const float tf = text[(size_t)(gr / Vn) * Dn + e];
        out[(size_t)gr * Dn + e] = fmaxf(tf * v1 + v2, 0.0f);
      }
    }
  }
}

// ---------------- kernel 4: conv1 -> relu -> conv2, in-place per row --------
__global__ __launch_bounds__(192) void conv_k(float* __restrict__ out,
                                              const float* __restrict__ cw1,
                                              const float* __restrict__ cb1,
                                              const float* __restrict__ cw2,
                                              const float* __restrict__ cb2) {
  __shared__ float buf[Dn];
  __shared__ float tmp[Dn];
  size_t row = blockIdx.x;
  float* p = out + row * Dn;
  int t = threadIdx.x;
  float4 v = ((const float4*)p)[t];
  ((float4*)buf)[t] = v;
  const float w10 = cw1[0], w11 = cw1[1], w12 = cw1[2], c1b = cb1[0];
  const float w20 = cw2[0], w21 = cw2[1], w22 = cw2[2], c2b = cb2[0];
  __syncthreads();
  float lm = t ? buf[t * 4 - 1] : 0.0f;
  float rp = (t < 191) ? buf[t * 4 + 4] : 0.0f;
  float4 c;
  c.x = fmaxf(w10 * lm  + w11 * v.x + w12 * v.y + c1b, 0.0f);
  c.y = fmaxf(w10 * v.x + w11 * v.y + w12 * v.z + c1b, 0.0f);
  c.z = fmaxf(w10 * v.y + w11 * v.z + w12 * v.w + c1b, 0.0f);
  c.w = fmaxf(w10 * v.z + w11 * v.w + w12 * rp  + c1b, 0.0f);
  ((float4*)tmp)[t] = c;
  __syncthreads();
  float lm2 = t ? tmp[t * 4 - 1] : 0.0f;
  float rp2 = (t < 191) ? tmp[t * 4 + 4] : 0.0f;
  float4 o;
  o.x = w20 * lm2 + w21 * c.x + w22 * c.y + c2b;
  o.y = w20 * c.x + w21 * c.y + w22 * c.z + c2b;
  o.z = w20 * c.y + w21 * c.z + w22 * c.w + c2b;
  o.w = w20 * c.z + w21 * c.w + w22 * rp2 + c2b;
  ((float4*)p)[t] = o;
}

extern "C" void kernel_launch(void* const* d_in, const int* in_sizes, int n_in,
                              void* d_out, int out_size, void* d_ws, size_t ws_size,
                              hipStream_t stream) {
  const float* text = (const float*)d_in[0];
  const float* vf   = (const float*)d_in[1];
  const float* W1   = (const float*)d_in[2];
  const float* b1   = (const float*)d_in[3];
  const float* W2   = (const float*)d_in[4];
  const float* b2   = (const float*)d_in[5];
  const float* cw1  = (const float*)d_in[6];
  const float* cb1  = (const float*)d_in[7];
  const float* cw2  = (const float*)d_in[8];
  const float* cb2  = (const float*)d_in[9];
  float* out = (float*)d_out;

  u16* X  = (u16*)d_ws;                       // [81920][768] bf16 softmax
  u16* Wt = (u16*)d_ws + (size_t)Mn * Dn;     // [1536][768] bf16 packed weights

  softmax_k<<<Mn, 192, 0, stream>>>(vf, X);
  build_wt_k<<<(Dn * Dn + 255) / 256, 256, 0, stream>>>(W1, W2, Wt);
  gemm_fuse_k<<<GRID, 512, 0, stream>>>(X, Wt, b1, b2, text, out);
  conv_k<<<Mn, 192, 0, stream>>>(out, cw1, cb1, cw2, cb2);
}

// Round 6
// 400.015 us; speedup vs baseline: 1.7099x; 1.0056x over previous
//
#include <hip/hip_runtime.h>

typedef unsigned short u16;
typedef __attribute__((ext_vector_type(8))) short short8;
typedef __attribute__((ext_vector_type(4))) float f32x4;

#define Bn 4096
#define Vn 20
#define Dn 768
#define Mn (Bn * Vn)   // 81920 rows
#define Nn (2 * Dn)    // 1536 packed m1/m2 columns

#define BM 256
#define BNt 256            // Wt rows per block tile (= 128 output e-columns)
#define HK 32              // K per slice
#define NHK (Dn / HK)      // 24 slices
#define NTILES (Nn / BNt)  // 6 N-tiles
#define GRID ((Mn / BM) * NTILES)   // 320 * 6 = 1920, %8 == 0
#define SLOTE 16384        // u16 per slot: A 256x32 (8192) + B 256x32 (8192)

typedef __attribute__((address_space(1))) void GV;
typedef __attribute__((address_space(3))) void LV;

__device__ __forceinline__ u16 f2bf(float f) {
  union { float f; unsigned u; } v; v.f = f;
  unsigned r = v.u + 0x7FFFu + ((v.u >> 16) & 1u);  // round-to-nearest-even
  return (u16)(r >> 16);
}

// LDS layout within a slot matrix region (256 rows x 32 K, u16):
//   u16 index = (r>>1)*64 + (r&1)*32 + (kc ^ ((r>>1)&3))*8 + j   (kc = K-chunk 0..3)
// Row-pair packed into 128B lines + 2-bit chunk XOR: conflict-free ds_read_b128
// (each 8-lane pass hits 8 distinct bank-quads — same criterion as the
// measured-zero R4/R5 pattern).
__device__ __forceinline__ int lds_off(int r, int hi) {
  return (r >> 1) * 64 + (r & 1) * 32 + ((hi ^ ((r >> 1) & 3)) * 8);
}

// ---------------- kernel 1: row softmax -> bf16 X ----------------
__global__ __launch_bounds__(192) void softmax_k(const float* __restrict__ vf,
                                                 u16* __restrict__ X) {
  size_t row = blockIdx.x;
  const float4* p = (const float4*)(vf + row * Dn);
  int t = threadIdx.x;
  float4 v = p[t];
  float mx = fmaxf(fmaxf(v.x, v.y), fmaxf(v.z, v.w));
  #pragma unroll
  for (int off = 32; off; off >>= 1) mx = fmaxf(mx, __shfl_xor(mx, off));
  __shared__ float rr[3];
  __shared__ float rs[3];
  int wv = t >> 6, ln = t & 63;
  if (!ln) rr[wv] = mx;
  __syncthreads();
  mx = fmaxf(fmaxf(rr[0], rr[1]), rr[2]);
  float e0 = __expf(v.x - mx), e1 = __expf(v.y - mx);
  float e2 = __expf(v.z - mx), e3 = __expf(v.w - mx);
  float s = e0 + e1 + e2 + e3;
  #pragma unroll
  for (int off = 32; off; off >>= 1) s += __shfl_xor(s, off);
  if (!ln) rs[wv] = s;
  __syncthreads();
  float inv = 1.0f / (rs[0] + rs[1] + rs[2]);
  ushort4 o;
  o.x = f2bf(e0 * inv); o.y = f2bf(e1 * inv);
  o.z = f2bf(e2 * inv); o.w = f2bf(e3 * inv);
  ((ushort4*)(X + row * Dn))[t] = o;
}

// ------- kernel 2: pack W1/W2 block-of-32 interleaved, bf16 [1536][768] -----
__global__ __launch_bounds__(256) void build_wt_k(const float* __restrict__ W1,
                                                  const float* __restrict__ W2,
                                                  u16* __restrict__ Wt) {
  int idx = blockIdx.x * 256 + threadIdx.x;
  if (idx >= Dn * Dn) return;
  int j = idx / Dn, d = idx - j * Dn;
  int b = j >> 5, c = j & 31;
  Wt[(size_t)(b * 64 + c) * Dn + d]      = f2bf(W1[(size_t)j * Dn + d]);
  Wt[(size_t)(b * 64 + 32 + c) * Dn + d] = f2bf(W2[(size_t)j * Dn + d]);
}

// -------- kernel 3: GEMM + fuse, 4-slot half-K ring, counted vmcnt ----------
// 8 waves (2M x 4N), wave tile 128x64. 24 K-slices of 32.
// Slice hk: vmcnt(8) [2 slices in flight, never drain] -> barrier ->
//   phase A: {stage A(hk+3) 2 loads; ds_read 4A+4B; lgkm0; prio1 16 MFMA prio0}
//   barrier ->
//   phase B: {stage B(hk+3) 2 loads; ds_read 4A;     lgkm0; prio1 16 MFMA prio0}
// Ring safety: slot (hk+3)%4 last read at hk-1, guarded by hk's top barrier.
__global__ __launch_bounds__(512, 2) void gemm_fuse_k(
    const u16* __restrict__ X, const u16* __restrict__ Wt,
    const float* __restrict__ b1, const float* __restrict__ b2,
    const float* __restrict__ text, float* __restrict__ out) {
  __shared__ __align__(16) u16 smem[4 * SLOTE];   // 128 KiB

  const int h = blockIdx.x;                      // GRID = 1920 blocks, %8==0
  const int lin = (h & 7) * (GRID / 8) + (h >> 3);
  const int by = lin / NTILES, bx = lin - by * NTILES;
  const int brow = by * BM;

  const int t = threadIdx.x, w = t >> 6, l = t & 63;
  const int lo = l & 15, hi = l >> 4;
  const int wrr = w >> 2, wcc = w & 3;

  // staging sources: thread q = i*512+t fills LDS u16 [q*8 .. q*8+8) of a region
  //   rp = q>>3, half = (q>>2)&1, chunk = q&3  ->  row rp*2+half, K-chunk chunk^(rp&3)
  const u16* gA[2];
  const u16* gB[2];
  #pragma unroll
  for (int i = 0; i < 2; ++i) {
    int q = i * 512 + t;
    int rp = q >> 3, half = (q >> 2) & 1, kc = (q & 3) ^ (rp & 3);
    gA[i] = X + (size_t)(brow + rp * 2 + half) * Dn + kc * 8;
    gB[i] = Wt + (size_t)(bx * BNt + rp * 2 + half) * Dn + kc * 8;
  }

#define STAGE_A(s, koff) do { _Pragma("unroll")                                \
    for (int i = 0; i < 2; ++i)                                                \
      __builtin_amdgcn_global_load_lds((GV*)(gA[i] + (koff)),                  \
          (LV*)(smem + (s) * SLOTE + (i * 512 + w * 64) * 8), 16, 0, 0);       \
  } while (0)
#define STAGE_B(s, koff) do { _Pragma("unroll")                                \
    for (int i = 0; i < 2; ++i)                                                \
      __builtin_amdgcn_global_load_lds((GV*)(gB[i] + (koff)),                  \
          (LV*)(smem + (s) * SLOTE + 8192 + (i * 512 + w * 64) * 8), 16, 0, 0);\
  } while (0)

  // prologue: slices 0,1,2 (12 loads in flight)
  STAGE_A(0, 0);       STAGE_B(0, 0);
  STAGE_A(1, HK);      STAGE_B(1, HK);
  STAGE_A(2, 2 * HK);  STAGE_B(2, 2 * HK);

  f32x4 acc[8][4] = {};

  for (int hk = 0; hk < NHK; ++hk) {
    // T4: counted wait — slice hk resident, slices hk+1,hk+2 (8 loads) in flight
    if (hk <= 21)      asm volatile("s_waitcnt vmcnt(8)" ::: "memory");
    else if (hk == 22) asm volatile("s_waitcnt vmcnt(4)" ::: "memory");
    else               asm volatile("s_waitcnt vmcnt(0)" ::: "memory");
    __builtin_amdgcn_s_barrier();

    const int slot = hk & 3;
    const bool st = (hk <= 20);
    const int skoff = (hk + 3) * HK;
    const u16* sa = smem + slot * SLOTE;
    const u16* sb = sa + 8192;
    short8 af[4], bfr[4];

    // ---- phase A: m-rows 0..63 of wave tile ----
    #pragma unroll
    for (int m = 0; m < 4; ++m)
      af[m] = *(const short8*)(sa + lds_off(wrr * 128 + m * 16 + lo, hi));
    #pragma unroll
    for (int n = 0; n < 4; ++n)
      bfr[n] = *(const short8*)(sb + lds_off(wcc * 64 + n * 16 + lo, hi));
    if (st) STAGE_A((hk + 3) & 3, skoff);
    asm volatile("s_waitcnt lgkmcnt(0)" ::: "memory");
    __builtin_amdgcn_sched_barrier(0);
    __builtin_amdgcn_s_setprio(1);
    #pragma unroll
    for (int m = 0; m < 4; ++m)
      #pragma unroll
      for (int n = 0; n < 4; ++n)
        acc[m][n] = __builtin_amdgcn_mfma_f32_16x16x32_bf16(af[m], bfr[n], acc[m][n], 0, 0, 0);
    __builtin_amdgcn_s_setprio(0);
    __builtin_amdgcn_s_barrier();

    // ---- phase B: m-rows 64..127 (bfr reused) ----
    #pragma unroll
    for (int m = 0; m < 4; ++m)
      af[m] = *(const short8*)(sa + lds_off(wrr * 128 + 64 + m * 16 + lo, hi));
    if (st) STAGE_B((hk + 3) & 3, skoff);
    asm volatile("s_waitcnt lgkmcnt(0)" ::: "memory");
    __builtin_amdgcn_sched_barrier(0);
    __builtin_amdgcn_s_setprio(1);
    #pragma unroll
    for (int m = 0; m < 4; ++m)
      #pragma unroll
      for (int n = 0; n < 4; ++n)
        acc[m + 4][n] = __builtin_amdgcn_mfma_f32_16x16x32_bf16(af[m], bfr[n], acc[m + 4][n], 0, 0, 0);
    __builtin_amdgcn_s_setprio(0);
  }
#undef STAGE_A
#undef STAGE_B

  // epilogue: m1 = acc[m][n], m2 = acc[m][n+2], same lane, same e
  const int ebase = (bx * 4 + wcc) * 32;
  #pragma unroll
  for (int n = 0; n < 2; ++n) {
    const int e = ebase + n * 16 + lo;
    const float B1 = b1[e], B2 = b2[e];
    #pragma unroll
    for (int m = 0; m < 8; ++m) {
      const int gr0 = brow + wrr * 128 + m * 16 + hi * 4;
      #pragma unroll
      for (int r = 0; r < 4; ++r) {
        const int gr = gr0 + r;
        const float v1 = acc[m][n][r] + B1;
        const float v2 = acc[m][n + 2][r] + B2;
        const float tf = text[(size_t)(gr / Vn) * Dn + e];
        out[(size_t)gr * Dn + e] = fmaxf(tf * v1 + v2, 0.0f);
      }
    }
  }
}

// ---------------- kernel 4: conv1 -> relu -> conv2, in-place per row --------
__global__ __launch_bounds__(192) void conv_k(float* __restrict__ out,
                                              const float* __restrict__ cw1,
                                              const float* __restrict__ cb1,
                                              const float* __restrict__ cw2,
                                              const float* __restrict__ cb2) {
  __shared__ float buf[Dn];
  __shared__ float tmp[Dn];
  size_t row = blockIdx.x;
  float* p = out + row * Dn;
  int t = threadIdx.x;
  float4 v = ((const float4*)p)[t];
  ((float4*)buf)[t] = v;
  const float w10 = cw1[0], w11 = cw1[1], w12 = cw1[2], c1b = cb1[0];
  const float w20 = cw2[0], w21 = cw2[1], w22 = cw2[2], c2b = cb2[0];
  __syncthreads();
  float lm = t ? buf[t * 4 - 1] : 0.0f;
  float rp = (t < 191) ? buf[t * 4 + 4] : 0.0f;
  float4 c;
  c.x = fmaxf(w10 * lm  + w11 * v.x + w12 * v.y + c1b, 0.0f);
  c.y = fmaxf(w10 * v.x + w11 * v.y + w12 * v.z + c1b, 0.0f);
  c.z = fmaxf(w10 * v.y + w11 * v.z + w12 * v.w + c1b, 0.0f);
  c.w = fmaxf(w10 * v.z + w11 * v.w + w12 * rp  + c1b, 0.0f);
  ((float4*)tmp)[t] = c;
  __syncthreads();
  float lm2 = t ? tmp[t * 4 - 1] : 0.0f;
  float rp2 = (t < 191) ? tmp[t * 4 + 4] : 0.0f;
  float4 o;
  o.x = w20 * lm2 + w21 * c.x + w22 * c.y + c2b;
  o.y = w20 * c.x + w21 * c.y + w22 * c.z + c2b;
  o.z = w20 * c.y + w21 * c.z + w22 * c.w + c2b;
  o.w = w20 * c.z + w21 * c.w + w22 * rp2 + c2b;
  ((float4*)p)[t] = o;
}

extern "C" void kernel_launch(void* const* d_in, const int* in_sizes, int n_in,
                              void* d_out, int out_size, void* d_ws, size_t ws_size,
                              hipStream_t stream) {
  const float* text = (const float*)d_in[0];
  const float* vf   = (const float*)d_in[1];
  const float* W1   = (const float*)d_in[2];
  const float* b1   = (const float*)d_in[3];
  const float* W2   = (const float*)d_in[4];
  const float* b2   = (const float*)d_in[5];
  const float* cw1  = (const float*)d_in[6];
  const float* cb1  = (const float*)d_in[7];
  const float* cw2  = (const float*)d_in[8];
  const float* cb2  = (const float*)d_in[9];
  float* out = (float*)d_out;

  u16* X  = (u16*)d_ws;                       // [81920][768] bf16 softmax
  u16* Wt = (u16*)d_ws + (size_t)Mn * Dn;     // [1536][768] bf16 packed weights

  softmax_k<<<Mn, 192, 0, stream>>>(vf, X);
  build_wt_k<<<(Dn * Dn + 255) / 256, 256, 0, stream>>>(W1, W2, Wt);
  gemm_fuse_k<<<GRID, 512, 0, stream>>>(X, Wt, b1, b2, text, out);
  conv_k<<<Mn, 192, 0, stream>>>(out, cw1, cb1, cw2, cb2);
}